// Round 14
// baseline (40.660 us; speedup 1.0000x reference)
//
#include <hip/hip_runtime.h>
#include <hip/hip_fp8.h>

typedef __attribute__((ext_vector_type(8))) short short8;
typedef __attribute__((ext_vector_type(4))) float f32x4;

// round-to-nearest-even f32 -> bf16
__device__ __forceinline__ unsigned short f2bf(float f) {
    unsigned u = __float_as_uint(f);
    u += 0x7FFFu + ((u >> 16) & 1u);
    return (unsigned short)(u >> 16);
}

__device__ __forceinline__ unsigned char f2fp8(float f) {
    __hip_fp8_e4m3 q(f);            // OCP e4m3fn, HW cvt on gfx950
    return q.__x;
}

// ---------------------------------------------------------------------------
// Prepass: convert x [Mpad*K] and w [N*K] f32 -> fp8 e4m3 in workspace.
// ---------------------------------------------------------------------------
__global__ void eventprop_cvt8_kernel(const float* __restrict__ x, const float* __restrict__ w,
                                      unsigned char* __restrict__ x8, unsigned char* __restrict__ w8,
                                      const int nx, const int ntot)
{
    const int i = blockIdx.x * blockDim.x + threadIdx.x;
    const int e0 = i * 8;
    if (e0 >= ntot) return;
    const float* src;
    unsigned char* dst;
    if (e0 < nx) { src = x + e0; dst = x8 + e0; }
    else         { src = w + (e0 - nx); dst = w8 + (e0 - nx); }
    const float4 f0 = *(const float4*)(src);
    const float4 f1 = *(const float4*)(src + 4);
    uchar4 a, b;
    a.x = f2fp8(f0.x); a.y = f2fp8(f0.y); a.z = f2fp8(f0.z); a.w = f2fp8(f0.w);
    b.x = f2fp8(f1.x); b.y = f2fp8(f1.y); b.z = f2fp8(f1.z); b.w = f2fp8(f1.w);
    uint2 v;
    v.x = *(unsigned int*)&a;
    v.y = *(unsigned int*)&b;
    *(uint2*)dst = v;               // 8B aligned (e0 % 8 == 0)
}

// ---------------------------------------------------------------------------
// Fused fp8 GEMM + scan, r11 K-loop (BK=128, both-sides 8-slot XOR swizzle,
// single-buffer) re-tiled for 8 INDEPENDENT blocks/CU:
//   tile 128(t) x 32(n), grid 64b x 32 = 2048 blocks, LDS 20KB -> 8 blocks/CU
//   (= 32 waves/CU, unsynced block-level overlap — the r4-proven lever).
//   4 waves as 2(t) x 2(n): wave-tile 64x16, acc[4][1] = 16 VGPR
//   (fits the 64-VGPR cap of __launch_bounds__(256,8)).
// Epilogue: acc -> cur f32 LDS [128][33] (16.9KB, aliases staging), barrier,
// lanes 0-31 of wave 0 scan 32 columns -> d_out.
// ---------------------------------------------------------------------------
__global__ __launch_bounds__(256, 8) void eventprop_gemm_scan_fp8_kernel(
    const unsigned char* __restrict__ X8, const unsigned char* __restrict__ W8,
    float* __restrict__ out, const int K, const int N, const int nbn)
{
    __shared__ __align__(16) unsigned char smem[20480];
    unsigned char* As = smem;                             // [128*128] fp8 (16 KB)
    unsigned char* Bs = smem + 16384;                     // [32*128]  fp8 (4 KB)
    float* curLds = (float*)smem;                         // [128][33] f32 (16.9 KB)

    // bijective XCD chunked swizzle (gridDim.x % 8 == 0); chunk = 8 b's/XCD
    const int bid0 = blockIdx.x;
    const int cpx = gridDim.x >> 3;                       // 256
    const int bid = (bid0 & 7) * cpx + (bid0 >> 3);
    const int bm = bid / nbn, bn = bid % nbn;             // bm = batch b, nbn = 32
    const int n0 = bn * 32;

    const int tid = threadIdx.x;
    const int lane = tid & 63;
    const int wave = tid >> 6;
    const int wr = wave >> 1, wc = wave & 1;     // 2x2 waves: 64(t) x 16(n) each
    const int lrow = lane & 15, kg = lane >> 4;  // MFMA fragment row / k-group
    const int srow = lane >> 3;                  // staging: row within 8-row group
    const int scol = (((lane & 7) ^ srow) * 16); // staging: SWIZZLED global byte col

    f32x4 acc[4] = {};

    for (int kt = 0; kt < K; kt += 128) {
        // ---- stage A (16 x 1KB issues, 4/wave) ----
        #pragma unroll
        for (int jj = 0; jj < 4; ++jj) {
            const int j = wave * 4 + jj;              // wave-uniform 0..15
            const int trow = j * 8 + srow;            // tile row = timestep t
            const unsigned char* ga = &X8[(size_t)(trow * 64 + bm) * K + kt + scol];
            __builtin_amdgcn_global_load_lds(
                (const __attribute__((address_space(1))) unsigned int*)ga,
                (__attribute__((address_space(3))) unsigned int*)&As[j * 1024], 16, 0, 0);
        }
        // ---- stage B (4 x 1KB issues, 1/wave) ----
        {
            const int j = wave;                       // wave-uniform 0..3
            const int row = j * 8 + srow;             // 0..31
            const unsigned char* gb = &W8[(size_t)(n0 + row) * K + kt + scol];
            __builtin_amdgcn_global_load_lds(
                (const __attribute__((address_space(1))) unsigned int*)gb,
                (__attribute__((address_space(3))) unsigned int*)&Bs[j * 1024], 16, 0, 0);
        }
        __syncthreads();   // drains vmcnt(0): tile ready

        // ---- 4 k-slices; per-ks fragment loads (VGPR cap) ----
        const int rx = (lrow & 7) << 4;              // read-side XOR term
        #pragma unroll
        for (int ks = 0; ks < 4; ++ks) {
            const int cc = (ks * 32 + kg * 8) ^ rx;  // 8B-aligned swizzled col
            long a[4], b;
            #pragma unroll
            for (int mi = 0; mi < 4; ++mi)
                a[mi] = *(const long*)&As[(wr * 64 + mi * 16 + lrow) * 128 + cc];
            b = *(const long*)&Bs[(wc * 16 + lrow) * 128 + cc];
            #pragma unroll
            for (int mi = 0; mi < 4; ++mi)
                acc[mi] = __builtin_amdgcn_mfma_f32_16x16x32_fp8_fp8(a[mi], b, acc[mi], 0, 0, 0);
        }
        __syncthreads();   // all waves done reading; LDS reusable
    }

    // ---- epilogue 1: acc -> curLds[t][col] f32, stride 33 (C/D layout m89) ----
    const int r0 = kg * 4;
    #pragma unroll
    for (int mi = 0; mi < 4; ++mi) {
        #pragma unroll
        for (int r = 0; r < 4; ++r) {
            const int t = wr * 64 + mi * 16 + r0 + r;
            const int col = wc * 16 + lrow;
            curLds[t * 33 + col] = acc[mi][r];
        }
    }
    __syncthreads();

    // ---- epilogue 2: per-column scan (lanes 0-31; 32 independent columns) ----
    if (tid < 32) {
        const int col = tid;
        const size_t obase = (size_t)bm * N + n0 + col;   // out[.][bm][n0+col]
        const int BO = 64 * N;                            // 65536
        float V = 0.f, I = 0.f;
        float c[8];
        #pragma unroll
        for (int p = 0; p < 8; ++p)
            c[p] = curLds[p * 33 + col];                  // cur[0..7]
        out[obase] = 0.f;                                 // out[0] = 0
        #pragma unroll 1
        for (int i = 0; i < 120; i += 8) {
            #pragma unroll
            for (int p = 0; p < 8; ++p) {
                const int it = i + p;                     // 0..119
                const float cn = curLds[(it + 8) * 33 + col];  // <=127 (127 = garbage, unused)
                const float Vn = 0.9f * V + 0.1f * I;
                const float s = (Vn > 1.0f) ? 1.0f : 0.0f;
                I = c[p];
                V = (1.0f - s) * Vn;
                out[(size_t)(it + 1) * BO + obase] = s;
                c[p] = cn;
            }
        }
        // tail: it = 120..126 (c[7] holds cur[127] garbage, never consumed)
        #pragma unroll
        for (int p = 0; p < 7; ++p) {
            const int it = 120 + p;
            const float Vn = 0.9f * V + 0.1f * I;
            const float s = (Vn > 1.0f) ? 1.0f : 0.0f;
            I = c[p];
            V = (1.0f - s) * Vn;
            out[(size_t)(it + 1) * BO + obase] = s;
        }
    }
}

// ---------------------------------------------------------------------------
// Fallback GEMM (inline f32->bf16, 128x128, BK=32, f32 cur to out) if ws small.
// ---------------------------------------------------------------------------
__global__ __launch_bounds__(256, 2) void eventprop_gemm_f32in_kernel(
    const float* __restrict__ X, const float* __restrict__ W, float* __restrict__ C,
    const int K, const int N, const int nbn)
{
    __shared__ unsigned short As[128][32];
    __shared__ unsigned short Bs[128][32];
    const int bid = blockIdx.x;
    const int bm = bid / nbn, bn = bid % nbn;
    const int m0 = bm * 128, n0 = bn * 128;
    const int tid = threadIdx.x;
    const int lane = tid & 63;
    const int wave = tid >> 6;
    const int wr = wave >> 1, wc = wave & 1;
    const int lrow = lane & 15, kg = lane >> 4;

    f32x4 acc[4][4] = {};
    for (int kt = 0; kt < K; kt += 32) {
        #pragma unroll
        for (int p = 0; p < 4; ++p) {
            const int idx = p * 256 + tid;
            const int row = idx >> 3;
            const int c4  = (idx & 7) * 4;
            const float4 fa = *(const float4*)&X[(size_t)(m0 + row) * K + kt + c4];
            ushort4 ua; ua.x = f2bf(fa.x); ua.y = f2bf(fa.y); ua.z = f2bf(fa.z); ua.w = f2bf(fa.w);
            *(ushort4*)&As[row][c4] = ua;
            const float4 fb = *(const float4*)&W[(size_t)(n0 + row) * K + kt + c4];
            ushort4 ub; ub.x = f2bf(fb.x); ub.y = f2bf(fb.y); ub.z = f2bf(fb.z); ub.w = f2bf(fb.w);
            *(ushort4*)&Bs[row][c4] = ub;
        }
        __syncthreads();
        short8 a[4], b[4];
        #pragma unroll
        for (int mi = 0; mi < 4; ++mi) a[mi] = *(const short8*)&As[wr * 64 + mi * 16 + lrow][kg * 8];
        #pragma unroll
        for (int ni = 0; ni < 4; ++ni) b[ni] = *(const short8*)&Bs[wc * 64 + ni * 16 + lrow][kg * 8];
        #pragma unroll
        for (int mi = 0; mi < 4; ++mi)
            #pragma unroll
            for (int ni = 0; ni < 4; ++ni)
                acc[mi][ni] = __builtin_amdgcn_mfma_f32_16x16x32_bf16(a[mi], b[ni], acc[mi][ni], 0, 0, 0);
        __syncthreads();
    }
    const int r0 = kg * 4;
    #pragma unroll
    for (int mi = 0; mi < 4; ++mi)
        #pragma unroll
        for (int ni = 0; ni < 4; ++ni)
            #pragma unroll
            for (int r = 0; r < 4; ++r)
                C[(size_t)(m0 + wr * 64 + mi * 16 + r0 + r) * N + (n0 + wc * 64 + ni * 16 + lrow)] = acc[mi][ni][r];
}

// ---------------------------------------------------------------------------
// Fallback scan: in-place on d_out (f32 cur), 8-deep prefetch ring.
// ---------------------------------------------------------------------------
__global__ void eventprop_scan_kernel(float* __restrict__ out, const int BO)
{
    const int idx = blockIdx.x * blockDim.x + threadIdx.x;
    float V = 0.f, I = 0.f;
    float c[8];
    #pragma unroll
    for (int p = 0; p < 8; ++p)
        c[p] = out[(size_t)p * BO + idx];
    out[idx] = 0.f;
    #pragma unroll 1
    for (int i = 0; i < 120; i += 8) {
        #pragma unroll
        for (int p = 0; p < 8; ++p) {
            const int it = i + p;
            const float cn = out[(size_t)(it + 8) * BO + idx];
            const float Vn = 0.9f * V + 0.1f * I;
            const float s = (Vn > 1.0f) ? 1.0f : 0.0f;
            I = c[p];
            V = (1.0f - s) * Vn;
            out[(size_t)(it + 1) * BO + idx] = s;
            c[p] = cn;
        }
    }
    #pragma unroll
    for (int p = 0; p < 7; ++p) {
        const int it = 120 + p;
        const float Vn = 0.9f * V + 0.1f * I;
        const float s = (Vn > 1.0f) ? 1.0f : 0.0f;
        I = c[p];
        V = (1.0f - s) * Vn;
        out[(size_t)(it + 1) * BO + idx] = s;
    }
}

extern "C" void kernel_launch(void* const* d_in, const int* in_sizes, int n_in,
                              void* d_out, int out_size, void* d_ws, size_t ws_size,
                              hipStream_t stream) {
    const float* x = (const float*)d_in[0];   // [T, B, IN] f32
    const float* w = (const float*)d_in[1];   // [OUT, IN] f32
    float* out = (float*)d_out;               // [T, B, OUT] f32

    const int T = 128, B = 64, IN = 1024, OUT = 1024;
    const int Mpad = T * B;                   // 8192
    const int BO = B * OUT;                   // 65536
    const size_t nx = (size_t)Mpad * IN;      // 8388608
    const size_t nw = (size_t)OUT * IN;       // 1048576
    const size_t need = nx + nw;              // 9.4 MB (fp8)

    if (ws_size >= need) {
        unsigned char* x8 = (unsigned char*)d_ws;
        unsigned char* w8 = x8 + nx;
        const int ntot = (int)(nx + nw);
        const int cvt_blocks = (ntot / 8 + 255) / 256;  // 4608
        eventprop_cvt8_kernel<<<dim3(cvt_blocks), dim3(256), 0, stream>>>(x, w, x8, w8, (int)nx, ntot);
        const int nbn = OUT / 32;                        // 32
        const int nblocks = B * nbn;                     // 64 * 32 = 2048
        eventprop_gemm_scan_fp8_kernel<<<dim3(nblocks), dim3(256), 0, stream>>>(x8, w8, out, IN, OUT, nbn);
    } else {
        const int nbn = OUT / 128;
        const int nblocks = (Mpad / 128) * nbn;          // 512
        eventprop_gemm_f32in_kernel<<<dim3(nblocks), dim3(256), 0, stream>>>(x, w, out, IN, OUT, nbn);
        eventprop_scan_kernel<<<dim3(BO / 256), dim3(256), 0, stream>>>(out, BO);
    }
}

// Round 15
// 34.866 us; speedup vs baseline: 1.1662x; 1.1662x over previous
//
#include <hip/hip_runtime.h>
#include <hip/hip_fp8.h>

typedef __attribute__((ext_vector_type(8))) short short8;
typedef __attribute__((ext_vector_type(4))) float f32x4;

// round-to-nearest-even f32 -> bf16
__device__ __forceinline__ unsigned short f2bf(float f) {
    unsigned u = __float_as_uint(f);
    u += 0x7FFFu + ((u >> 16) & 1u);
    return (unsigned short)(u >> 16);
}

__device__ __forceinline__ unsigned char f2fp8(float f) {
    __hip_fp8_e4m3 q(f);            // OCP e4m3fn, HW cvt on gfx950
    return q.__x;
}

// ---------------------------------------------------------------------------
// Prepass: convert x [Mpad*K] and w [N*K] f32 -> fp8 e4m3 in workspace.
// ---------------------------------------------------------------------------
__global__ void eventprop_cvt8_kernel(const float* __restrict__ x, const float* __restrict__ w,
                                      unsigned char* __restrict__ x8, unsigned char* __restrict__ w8,
                                      const int nx, const int ntot)
{
    const int i = blockIdx.x * blockDim.x + threadIdx.x;
    const int e0 = i * 8;
    if (e0 >= ntot) return;
    const float* src;
    unsigned char* dst;
    if (e0 < nx) { src = x + e0; dst = x8 + e0; }
    else         { src = w + (e0 - nx); dst = w8 + (e0 - nx); }
    const float4 f0 = *(const float4*)(src);
    const float4 f1 = *(const float4*)(src + 4);
    uchar4 a, b;
    a.x = f2fp8(f0.x); a.y = f2fp8(f0.y); a.z = f2fp8(f0.z); a.w = f2fp8(f0.w);
    b.x = f2fp8(f1.x); b.y = f2fp8(f1.y); b.z = f2fp8(f1.z); b.w = f2fp8(f1.w);
    uint2 v;
    v.x = *(unsigned int*)&a;
    v.y = *(unsigned int*)&b;
    *(uint2*)dst = v;               // 8B aligned (e0 % 8 == 0)
}

// ---------------------------------------------------------------------------
// Fused fp8 GEMM + scan (round-11 optimum). 128x64 tile, BK=128, 4 waves
// (2x2, 64x32 each), single-buffer, __syncthreads; both-sides 8-slot 16B
// XOR swizzle (rule #21); XCD chunked blockIdx swizzle; 4 blocks/CU.
// Time-tiled grid: block (bm=b, bn) computes A-rows {t*64+b, t=0..127}.
// Epilogue: acc -> LDS cur[128][65] f32 (aliases As/Bs; stride-65), barrier,
// wave 0 scans 64 independent columns writing spikes straight to d_out.
// ---------------------------------------------------------------------------
__global__ __launch_bounds__(256, 4) void eventprop_gemm_scan_fp8_kernel(
    const unsigned char* __restrict__ X8, const unsigned char* __restrict__ W8,
    float* __restrict__ out, const int K, const int N, const int nbn)
{
    __shared__ float smemf[128 * 65];                     // 33280 B
    unsigned char* As = (unsigned char*)smemf;            // [128*128] fp8 (16 KB)
    unsigned char* Bs = As + 16384;                       // [64*128]  fp8 (8 KB)
    float* curLds = smemf;                                // [128][65] f32 (after K-loop)

    // bijective XCD chunked swizzle (gridDim.x % 8 == 0); groups same-b blocks
    const int bid0 = blockIdx.x;
    const int cpx = gridDim.x >> 3;                       // 128
    const int bid = (bid0 & 7) * cpx + (bid0 >> 3);
    const int bm = bid / nbn, bn = bid % nbn;             // bm = batch b, nbn = 16
    const int n0 = bn * 64;

    const int tid = threadIdx.x;
    const int lane = tid & 63;
    const int wave = tid >> 6;
    const int wr = wave >> 1, wc = wave & 1;     // 2x2 waves: 64(t) x 32(n) each
    const int lrow = lane & 15, kg = lane >> 4;  // MFMA fragment row / k-group
    const int srow = lane >> 3;                  // staging: row within 8-row group
    const int scol = (((lane & 7) ^ srow) * 16); // staging: SWIZZLED global byte col

    f32x4 acc[4][2] = {};

    for (int kt = 0; kt < K; kt += 128) {
        // ---- stage A (16 x 1KB issues, 4/wave) + B (8 issues, 2/wave) ----
        #pragma unroll
        for (int jj = 0; jj < 4; ++jj) {
            const int j = wave * 4 + jj;              // wave-uniform 0..15
            const int trow = j * 8 + srow;            // tile row = timestep t
            const unsigned char* ga = &X8[(size_t)(trow * 64 + bm) * K + kt + scol];
            __builtin_amdgcn_global_load_lds(
                (const __attribute__((address_space(1))) unsigned int*)ga,
                (__attribute__((address_space(3))) unsigned int*)&As[j * 1024], 16, 0, 0);
        }
        #pragma unroll
        for (int jj = 0; jj < 2; ++jj) {
            const int j = wave * 2 + jj;              // wave-uniform 0..7
            const int row = j * 8 + srow;
            const unsigned char* gb = &W8[(size_t)(n0 + row) * K + kt + scol];
            __builtin_amdgcn_global_load_lds(
                (const __attribute__((address_space(1))) unsigned int*)gb,
                (__attribute__((address_space(3))) unsigned int*)&Bs[j * 1024], 16, 0, 0);
        }
        __syncthreads();   // drains vmcnt(0): tile ready

        // ---- fragments + MFMA: 4 k-slices of 32, swizzled ds_read cols ----
        const int rx = (lrow & 7) << 4;              // read-side XOR term
        long a[4][4], b[4][2];
        #pragma unroll
        for (int ks = 0; ks < 4; ++ks) {
            const int cc = (ks * 32 + kg * 8) ^ rx;  // 8B-aligned swizzled col
            #pragma unroll
            for (int mi = 0; mi < 4; ++mi)
                a[ks][mi] = *(const long*)&As[(wr * 64 + mi * 16 + lrow) * 128 + cc];
            #pragma unroll
            for (int ni = 0; ni < 2; ++ni)
                b[ks][ni] = *(const long*)&Bs[(wc * 32 + ni * 16 + lrow) * 128 + cc];
        }
        #pragma unroll
        for (int ks = 0; ks < 4; ++ks)
            #pragma unroll
            for (int mi = 0; mi < 4; ++mi)
                #pragma unroll
                for (int ni = 0; ni < 2; ++ni)
                    acc[mi][ni] = __builtin_amdgcn_mfma_f32_16x16x32_fp8_fp8(
                        a[ks][mi], b[ks][ni], acc[mi][ni], 0, 0, 0);
        __syncthreads();   // all waves done reading; LDS reusable
    }

    // ---- epilogue 1: acc -> curLds[t][col], stride 65 (C/D layout m89) ----
    const int r0 = kg * 4;
    #pragma unroll
    for (int mi = 0; mi < 4; ++mi) {
        #pragma unroll
        for (int ni = 0; ni < 2; ++ni) {
            #pragma unroll
            for (int r = 0; r < 4; ++r) {
                const int t = wr * 64 + mi * 16 + r0 + r;
                const int col = wc * 32 + ni * 16 + lrow;
                curLds[t * 65 + col] = acc[mi][ni][r];
            }
        }
    }
    __syncthreads();

    // ---- epilogue 2: per-column scan (wave 0; 64 independent columns) ----
    if (tid < 64) {
        const int col = tid;
        const size_t obase = (size_t)bm * N + n0 + col;   // out[.][bm][n0+col]
        const int BO = 64 * N;                            // 65536
        float V = 0.f, I = 0.f;
        float c[8];
        #pragma unroll
        for (int p = 0; p < 8; ++p)
            c[p] = curLds[p * 65 + col];                  // cur[0..7]
        out[obase] = 0.f;                                 // out[0] = 0
        #pragma unroll 1
        for (int i = 0; i < 120; i += 8) {
            #pragma unroll
            for (int p = 0; p < 8; ++p) {
                const int it = i + p;                     // 0..119
                const float cn = curLds[(it + 8) * 65 + col];  // <=127 (127 = garbage, unused)
                const float Vn = 0.9f * V + 0.1f * I;
                const float s = (Vn > 1.0f) ? 1.0f : 0.0f;
                I = c[p];
                V = (1.0f - s) * Vn;
                out[(size_t)(it + 1) * BO + obase] = s;
                c[p] = cn;
            }
        }
        // tail: it = 120..126 (c[7] holds cur[127] garbage, never consumed)
        #pragma unroll
        for (int p = 0; p < 7; ++p) {
            const int it = 120 + p;
            const float Vn = 0.9f * V + 0.1f * I;
            const float s = (Vn > 1.0f) ? 1.0f : 0.0f;
            I = c[p];
            V = (1.0f - s) * Vn;
            out[(size_t)(it + 1) * BO + obase] = s;
        }
    }
}

// ---------------------------------------------------------------------------
// Fallback GEMM (inline f32->bf16, 128x128, BK=32, f32 cur to out) if ws small.
// ---------------------------------------------------------------------------
__global__ __launch_bounds__(256, 2) void eventprop_gemm_f32in_kernel(
    const float* __restrict__ X, const float* __restrict__ W, float* __restrict__ C,
    const int K, const int N, const int nbn)
{
    __shared__ unsigned short As[128][32];
    __shared__ unsigned short Bs[128][32];
    const int bid = blockIdx.x;
    const int bm = bid / nbn, bn = bid % nbn;
    const int m0 = bm * 128, n0 = bn * 128;
    const int tid = threadIdx.x;
    const int lane = tid & 63;
    const int wave = tid >> 6;
    const int wr = wave >> 1, wc = wave & 1;
    const int lrow = lane & 15, kg = lane >> 4;

    f32x4 acc[4][4] = {};
    for (int kt = 0; kt < K; kt += 32) {
        #pragma unroll
        for (int p = 0; p < 4; ++p) {
            const int idx = p * 256 + tid;
            const int row = idx >> 3;
            const int c4  = (idx & 7) * 4;
            const float4 fa = *(const float4*)&X[(size_t)(m0 + row) * K + kt + c4];
            ushort4 ua; ua.x = f2bf(fa.x); ua.y = f2bf(fa.y); ua.z = f2bf(fa.z); ua.w = f2bf(fa.w);
            *(ushort4*)&As[row][c4] = ua;
            const float4 fb = *(const float4*)&W[(size_t)(n0 + row) * K + kt + c4];
            ushort4 ub; ub.x = f2bf(fb.x); ub.y = f2bf(fb.y); ub.z = f2bf(fb.z); ub.w = f2bf(fb.w);
            *(ushort4*)&Bs[row][c4] = ub;
        }
        __syncthreads();
        short8 a[4], b[4];
        #pragma unroll
        for (int mi = 0; mi < 4; ++mi) a[mi] = *(const short8*)&As[wr * 64 + mi * 16 + lrow][kg * 8];
        #pragma unroll
        for (int ni = 0; ni < 4; ++ni) b[ni] = *(const short8*)&Bs[wc * 64 + ni * 16 + lrow][kg * 8];
        #pragma unroll
        for (int mi = 0; mi < 4; ++mi)
            #pragma unroll
            for (int ni = 0; ni < 4; ++ni)
                acc[mi][ni] = __builtin_amdgcn_mfma_f32_16x16x32_bf16(a[mi], b[ni], acc[mi][ni], 0, 0, 0);
        __syncthreads();
    }
    const int r0 = kg * 4;
    #pragma unroll
    for (int mi = 0; mi < 4; ++mi)
        #pragma unroll
        for (int ni = 0; ni < 4; ++ni)
            #pragma unroll
            for (int r = 0; r < 4; ++r)
                C[(size_t)(m0 + wr * 64 + mi * 16 + r0 + r) * N + (n0 + wc * 64 + ni * 16 + lrow)] = acc[mi][ni][r];
}

// ---------------------------------------------------------------------------
// Fallback scan: in-place on d_out (f32 cur), 8-deep prefetch ring.
// ---------------------------------------------------------------------------
__global__ void eventprop_scan_kernel(float* __restrict__ out, const int BO)
{
    const int idx = blockIdx.x * blockDim.x + threadIdx.x;
    float V = 0.f, I = 0.f;
    float c[8];
    #pragma unroll
    for (int p = 0; p < 8; ++p)
        c[p] = out[(size_t)p * BO + idx];
    out[idx] = 0.f;
    #pragma unroll 1
    for (int i = 0; i < 120; i += 8) {
        #pragma unroll
        for (int p = 0; p < 8; ++p) {
            const int it = i + p;
            const float cn = out[(size_t)(it + 8) * BO + idx];
            const float Vn = 0.9f * V + 0.1f * I;
            const float s = (Vn > 1.0f) ? 1.0f : 0.0f;
            I = c[p];
            V = (1.0f - s) * Vn;
            out[(size_t)(it + 1) * BO + idx] = s;
            c[p] = cn;
        }
    }
    #pragma unroll
    for (int p = 0; p < 7; ++p) {
        const int it = 120 + p;
        const float Vn = 0.9f * V + 0.1f * I;
        const float s = (Vn > 1.0f) ? 1.0f : 0.0f;
        I = c[p];
        V = (1.0f - s) * Vn;
        out[(size_t)(it + 1) * BO + idx] = s;
    }
}

extern "C" void kernel_launch(void* const* d_in, const int* in_sizes, int n_in,
                              void* d_out, int out_size, void* d_ws, size_t ws_size,
                              hipStream_t stream) {
    const float* x = (const float*)d_in[0];   // [T, B, IN] f32
    const float* w = (const float*)d_in[1];   // [OUT, IN] f32
    float* out = (float*)d_out;               // [T, B, OUT] f32

    const int T = 128, B = 64, IN = 1024, OUT = 1024;
    const int Mpad = T * B;                   // 8192
    const int BO = B * OUT;                   // 65536
    const size_t nx = (size_t)Mpad * IN;      // 8388608
    const size_t nw = (size_t)OUT * IN;       // 1048576
    const size_t need = nx + nw;              // 9.4 MB (fp8)

    if (ws_size >= need) {
        unsigned char* x8 = (unsigned char*)d_ws;
        unsigned char* w8 = x8 + nx;
        const int ntot = (int)(nx + nw);
        const int cvt_blocks = (ntot / 8 + 255) / 256;  // 4608
        eventprop_cvt8_kernel<<<dim3(cvt_blocks), dim3(256), 0, stream>>>(x, w, x8, w8, (int)nx, ntot);
        const int nbn = OUT / 64;                        // 16
        const int nblocks = B * nbn;                     // 64 * 16 = 1024
        eventprop_gemm_scan_fp8_kernel<<<dim3(nblocks), dim3(256), 0, stream>>>(x8, w8, out, IN, OUT, nbn);
    } else {
        const int nbn = OUT / 128;
        const int nblocks = (Mpad / 128) * nbn;          // 512
        eventprop_gemm_f32in_kernel<<<dim3(nblocks), dim3(256), 0, stream>>>(x, w, out, IN, OUT, nbn);
        eventprop_scan_kernel<<<dim3(BO / 256), dim3(256), 0, stream>>>(out, BO);
    }
}